// Round 7
// baseline (355.632 us; speedup 1.0000x reference)
//
#include <hip/hip_runtime.h>
#include <hip/hip_cooperative_groups.h>
#include <hip/hip_bf16.h>
#include <stdint.h>

namespace cg = cooperative_groups;

#define NQ 16384   // 128*128 guide positions
#define NL 1024    // 32*32 low positions

typedef __bf16 bf16_t;
typedef __bf16 bf16x8 __attribute__((ext_vector_type(8)));
typedef __bf16 bf16x4 __attribute__((ext_vector_type(4)));
typedef float f32x4 __attribute__((ext_vector_type(4)));

__device__ __forceinline__ void gload_lds16(const void* g, void* l) {
  __builtin_amdgcn_global_load_lds(
      (const __attribute__((address_space(1))) uint32_t*)g,
      (__attribute__((address_space(3))) uint32_t*)l, 16, 0, 0);
}

// ---- transposes (d-major fp32 -> n-major bf16) + weight cvt, ONE launch ----
__global__ __launch_bounds__(256) void cvt_all(const float* __restrict__ guide,
                                               const float* __restrict__ low,
                                               const float* __restrict__ Wq,
                                               const float* __restrict__ Wk,
                                               const float* __restrict__ Wv,
                                               const float* __restrict__ Wm,
                                               bf16_t* __restrict__ Gbf,
                                               bf16_t* __restrict__ Lbf,
                                               bf16_t* __restrict__ Wall) {
  const int bx = blockIdx.x, by = blockIdx.y, t = threadIdx.x;
  if (bx >= 544) {
    const int idx = (((bx - 544) * 16 + by) * 256 + t) * 4;
    const float* s;
    int off;
    if (idx < 262144)      { s = Wq; off = idx; }
    else if (idx < 524288) { s = Wk; off = idx - 262144; }
    else if (idx < 786432) { s = Wv; off = idx - 524288; }
    else                   { s = Wm; off = idx - 786432; }
    float4 v = *(const float4*)(s + off);
    bf16x4 o = {(bf16_t)v.x, (bf16_t)v.y, (bf16_t)v.z, (bf16_t)v.w};
    *(bf16x4*)(Wall + idx) = o;
    return;
  }
  __shared__ float tl[32][33];
  const float* src;
  bf16_t* dst;
  int ncols, n0;
  if (bx < 512) { src = guide; dst = Gbf; ncols = NQ; n0 = bx * 32; }
  else          { src = low;   dst = Lbf; ncols = NL; n0 = (bx - 512) * 32; }
  const int c0 = by * 32;
  const int c = t & 31, r = t >> 5;
#pragma unroll
  for (int it = 0; it < 4; ++it) {
    int rr = r + it * 8;
    tl[rr][c] = src[(size_t)(c0 + rr) * ncols + n0 + c];
  }
  __syncthreads();
#pragma unroll
  for (int it = 0; it < 4; ++it) {
    int rr = r + it * 8;
    dst[(size_t)(n0 + rr) * 512 + c0 + c] = (bf16_t)tl[c][rr];
  }
}

// ================= cooperative mega-kernel: qkv GEMM -> attn -> Wm GEMM + LN =================
// 256 blocks x 512 threads, 1 block/CU (150 KB LDS), grid.sync() between phases
__global__ __launch_bounds__(512, 1) void mega(const bf16_t* __restrict__ Gbf,
                                               const bf16_t* __restrict__ Lbf,
                                               const bf16_t* __restrict__ Wall,
                                               bf16_t* __restrict__ Qbf,
                                               bf16_t* __restrict__ KVbf,
                                               bf16_t* __restrict__ Msg,
                                               const float* __restrict__ gamma,
                                               const float* __restrict__ beta,
                                               float* __restrict__ out) {
  __shared__ __align__(16) char smem[147456];
  __shared__ float2 part[64][4];
  __shared__ float2 st[64];
  cg::grid_group grid = cg::this_grid();
  const int bid = blockIdx.x;
  const int t = threadIdx.x;
  const int lane = t & 63;
  const int wave = t >> 6;

  // ---------------- phase 1: Q/K/V projections (jobs 0..575, 128x128 tiles) ----------------
  {
    bf16_t* const As0 = (bf16_t*)smem;              // 16 KB
    bf16_t* const As1 = (bf16_t*)(smem + 16384);
    bf16_t* const Bs0 = (bf16_t*)(smem + 32768);
    bf16_t* const Bs1 = (bf16_t*)(smem + 49152);
    const int r0 = t >> 3;          // staging row 0..63
    const int c0e = (t & 7) * 8;    // staging col (elements)
    const int wr = (wave >> 1) * 32;  // 8 waves: 4 row x 2 col
    const int wc = (wave & 1) * 64;
    const int fr = lane & 15;
    const int fk = (lane >> 4) * 8;
    for (int job = bid; job < 576; job += 256) {
      const bf16_t *A, *B;
      bf16_t* C;
      int N, bm, bn;
      if (job < 512) { A = Gbf; B = Wall; C = Qbf; N = 512; bm = (job >> 2) * 128; bn = (job & 3) * 128; }
      else { int j = job - 512; A = Lbf; B = Wall + 262144; C = KVbf; N = 1024; bm = (j >> 3) * 128; bn = (j & 7) * 128; }
#pragma unroll
      for (int it = 0; it < 2; ++it) {  // prologue: K-tile 0 -> buf 0
        const int r = r0 + it * 64;
        gload_lds16(A + (size_t)(bm + r) * 512 + c0e, &As0[r * 64 + c0e]);
        gload_lds16(B + (size_t)(bn + r) * 512 + c0e, &Bs0[r * 64 + c0e]);
      }
      f32x4 acc[2][4] = {};
      __syncthreads();
#pragma unroll 2
      for (int kt = 0; kt < 8; ++kt) {
        bf16_t* const Ac = (kt & 1) ? As1 : As0;
        bf16_t* const Bc = (kt & 1) ? Bs1 : Bs0;
        bf16_t* const An = (kt & 1) ? As0 : As1;
        bf16_t* const Bn = (kt & 1) ? Bs0 : Bs1;
        if (kt < 7) {
          const int k0 = (kt + 1) * 64;
#pragma unroll
          for (int it = 0; it < 2; ++it) {
            const int r = r0 + it * 64;
            gload_lds16(A + (size_t)(bm + r) * 512 + k0 + c0e, &An[r * 64 + c0e]);
            gload_lds16(B + (size_t)(bn + r) * 512 + k0 + c0e, &Bn[r * 64 + c0e]);
          }
        }
        __builtin_amdgcn_sched_barrier(0);
#pragma unroll
        for (int kk = 0; kk < 2; ++kk) {
          bf16x8 af[2], bv[4];
#pragma unroll
          for (int i = 0; i < 2; ++i)
            af[i] = *(const bf16x8*)&Ac[(wr + i * 16 + fr) * 64 + kk * 32 + fk];
#pragma unroll
          for (int j = 0; j < 4; ++j)
            bv[j] = *(const bf16x8*)&Bc[(wc + j * 16 + fr) * 64 + kk * 32 + fk];
#pragma unroll
          for (int i = 0; i < 2; ++i)
#pragma unroll
            for (int j = 0; j < 4; ++j)
              acc[i][j] = __builtin_amdgcn_mfma_f32_16x16x32_bf16(af[i], bv[j], acc[i][j], 0, 0, 0);
        }
        __syncthreads();
      }
      const int crow = bm + wr + ((lane >> 4) * 4);
      const int ccol = bn + wc + fr;
#pragma unroll
      for (int i = 0; i < 2; ++i)
#pragma unroll
        for (int j = 0; j < 4; ++j)
#pragma unroll
          for (int v = 0; v < 4; ++v)
            C[(size_t)(crow + i * 16 + v) * N + ccol + j * 16] = (bf16_t)acc[i][j][v];
    }
  }
  __threadfence();
  grid.sync();

  // ---------------- phase 2: windowed attention (4 tiles per block) ----------------
  {
    bf16_t* const Kl = (bf16_t*)smem;            // 9*512 bf16 = 9 KB
    bf16_t* const Vl = (bf16_t*)(smem + 9216);
    for (int tile = bid; tile < 1024; tile += 256) {
      const int ty = tile >> 5, tx = tile & 31;
      for (int kk = wave; kk < 9; kk += 8) {
        int ky = kk / 3, kx = kk - ky * 3;
        int yy = min(max(ty - 1 + ky, 0), 31);
        int xx = min(max(tx - 1 + kx, 0), 31);
        size_t p = (size_t)(yy * 32 + xx) * 1024;
        *(bf16x8*)&Kl[kk * 512 + lane * 8] = *(const bf16x8*)&KVbf[p + lane * 8];
        *(bf16x8*)&Vl[kk * 512 + lane * 8] = *(const bf16x8*)&KVbf[p + 512 + lane * 8];
      }
      __syncthreads();
      const int c = t & 3;
      const int h = (t >> 2) & 7;
      const int pl = t >> 5;
      const int y = ty * 4 + (pl >> 2), x = tx * 4 + (pl & 3);
      const size_t n = (size_t)y * 128 + x;
      const int doff = h * 64 + c * 16;
      const bf16x8 q0 = *(const bf16x8*)(Qbf + n * 512 + doff);
      const bf16x8 q1 = *(const bf16x8*)(Qbf + n * 512 + doff + 8);
      float s[9];
#pragma unroll
      for (int k = 0; k < 9; ++k) {
        bf16x8 k0 = *(const bf16x8*)&Kl[k * 512 + doff];
        bf16x8 k1 = *(const bf16x8*)&Kl[k * 512 + doff + 8];
        float p = 0.f;
#pragma unroll
        for (int e = 0; e < 8; ++e) p += (float)q0[e] * (float)k0[e] + (float)q1[e] * (float)k1[e];
        p += __shfl_xor(p, 1, 64);
        p += __shfl_xor(p, 2, 64);
        s[k] = p;
      }
      float mx = s[0];
#pragma unroll
      for (int k = 1; k < 9; ++k) mx = fmaxf(mx, s[k]);
      float sum = 0.f;
#pragma unroll
      for (int k = 0; k < 9; ++k) {
        s[k] = __expf((s[k] - mx) * 0.125f);
        sum += s[k];
      }
      const float inv = 1.0f / sum;
      float accv[16] = {};
#pragma unroll
      for (int k = 0; k < 9; ++k) {
        const float p = s[k] * inv;
        bf16x8 v0 = *(const bf16x8*)&Vl[k * 512 + doff];
        bf16x8 v1 = *(const bf16x8*)&Vl[k * 512 + doff + 8];
#pragma unroll
        for (int e = 0; e < 8; ++e) {
          accv[e] += p * (float)v0[e];
          accv[8 + e] += p * (float)v1[e];
        }
      }
      bf16x8 o0, o1;
#pragma unroll
      for (int e = 0; e < 8; ++e) { o0[e] = (bf16_t)accv[e]; o1[e] = (bf16_t)accv[8 + e]; }
      *(bf16x8*)(Msg + n * 512 + doff) = o0;
      *(bf16x8*)(Msg + n * 512 + doff + 8) = o1;
      __syncthreads();
    }
  }
  __threadfence();
  grid.sync();

  // ---------------- phase 3: P = Msg @ Wm^T, LayerNorm, transposed write ----------------
  {
    const bf16_t* const A = Msg;
    const bf16_t* const B = Wall + 786432;
    bf16_t* const As0 = (bf16_t*)smem;              // 8 KB
    bf16_t* const As1 = (bf16_t*)(smem + 8192);
    bf16_t* const Bs0 = (bf16_t*)(smem + 16384);    // 64 KB
    bf16_t* const Bs1 = (bf16_t*)(smem + 81920);
    float* const Cl = (float*)smem;                 // [64][513] fp32 overlay
    const int wr = (wave >> 2) * 32;
    const int wc = (wave & 3) * 128;
    const int bm = bid * 64;
    const int sr = t >> 3;
    const int sc = (t & 7) * 8;
    const int fr = lane & 15;
    const int fk = (lane >> 4) * 8;
    gload_lds16(A + (size_t)(bm + sr) * 512 + sc, &As0[sr * 64 + sc]);
#pragma unroll
    for (int it = 0; it < 8; ++it) {
      const int r = sr + it * 64;
      gload_lds16(B + (size_t)r * 512 + sc, &Bs0[r * 64 + sc]);
    }
    f32x4 acc[2][8] = {};
    __syncthreads();
#pragma unroll 2
    for (int kt = 0; kt < 8; ++kt) {
      bf16_t* const Asc = (kt & 1) ? As1 : As0;
      bf16_t* const Bsc = (kt & 1) ? Bs1 : Bs0;
      bf16_t* const Asn = (kt & 1) ? As0 : As1;
      bf16_t* const Bsn = (kt & 1) ? Bs0 : Bs1;
      if (kt < 7) {
        const int k0 = (kt + 1) * 64;
        gload_lds16(A + (size_t)(bm + sr) * 512 + k0 + sc, &Asn[sr * 64 + sc]);
#pragma unroll
        for (int it = 0; it < 8; ++it) {
          const int r = sr + it * 64;
          gload_lds16(B + (size_t)r * 512 + k0 + sc, &Bsn[r * 64 + sc]);
        }
      }
      __builtin_amdgcn_sched_barrier(0);
#pragma unroll
      for (int kk = 0; kk < 2; ++kk) {
        bf16x8 af[2], bfv[8];
#pragma unroll
        for (int i = 0; i < 2; ++i)
          af[i] = *(const bf16x8*)&Asc[(wr + i * 16 + fr) * 64 + kk * 32 + fk];
#pragma unroll
        for (int j = 0; j < 8; ++j)
          bfv[j] = *(const bf16x8*)&Bsc[(wc + j * 16 + fr) * 64 + kk * 32 + fk];
#pragma unroll
        for (int i = 0; i < 2; ++i)
#pragma unroll
          for (int j = 0; j < 8; ++j)
            acc[i][j] = __builtin_amdgcn_mfma_f32_16x16x32_bf16(af[i], bfv[j], acc[i][j], 0, 0, 0);
      }
      __syncthreads();
    }
#pragma unroll
    for (int i = 0; i < 2; ++i)
#pragma unroll
      for (int j = 0; j < 8; ++j) {
        const int row = wr + i * 16 + (lane >> 4) * 4;
        const int col = wc + j * 16 + fr;
#pragma unroll
        for (int v = 0; v < 4; ++v) Cl[(row + v) * 513 + col] = acc[i][j][v];
      }
#pragma unroll
    for (int i = 0; i < 2; ++i)
#pragma unroll
      for (int v = 0; v < 4; ++v) {
        float s = 0.f, s2 = 0.f;
#pragma unroll
        for (int j = 0; j < 8; ++j) {
          float x = acc[i][j][v];
          s += x;
          s2 += x * x;
        }
#pragma unroll
        for (int m = 1; m < 16; m <<= 1) {
          s += __shfl_xor(s, m, 64);
          s2 += __shfl_xor(s2, m, 64);
        }
        if ((lane & 15) == 0) {
          const int row = wr + i * 16 + (lane >> 4) * 4 + v;
          part[row][wave & 3] = make_float2(s, s2);
        }
      }
    __syncthreads();
    if (t < 64) {
      float2 p0 = part[t][0], p1 = part[t][1], p2 = part[t][2], p3 = part[t][3];
      float s = p0.x + p1.x + p2.x + p3.x;
      float s2 = p0.y + p1.y + p2.y + p3.y;
      float mu = s * (1.f / 512.f);
      float var = s2 * (1.f / 512.f) - mu * mu;
      st[t] = make_float2(mu, rsqrtf(var + 1e-5f));
    }
    __syncthreads();
    const int n = t & 63;
    const int j0 = t >> 6;
    const float2 ms = st[n];
#pragma unroll 8
    for (int jj = 0; jj < 64; ++jj) {
      const int j = j0 * 64 + jj;
      const float g = gamma[j], b = beta[j];
      const float x = Cl[n * 513 + j];
      out[(size_t)j * NQ + bm + n] = (x - ms.x) * ms.y * g + b;
    }
  }
}

extern "C" void kernel_launch(void* const* d_in, const int* in_sizes, int n_in,
                              void* d_out, int out_size, void* d_ws, size_t ws_size,
                              hipStream_t stream) {
  const float* low = (const float*)d_in[0];
  const float* guide = (const float*)d_in[1];
  const float* Wq = (const float*)d_in[2];
  const float* Wk = (const float*)d_in[3];
  const float* Wv = (const float*)d_in[4];
  const float* Wm = (const float*)d_in[5];
  const float* gamma = (const float*)d_in[6];
  const float* beta = (const float*)d_in[7];
  float* out = (float*)d_out;

  char* w = (char*)d_ws;
  bf16_t* Gbf = (bf16_t*)w;  w += (size_t)NQ * 512 * 2;
  bf16_t* Lbf = (bf16_t*)w;  w += (size_t)NL * 512 * 2;
  bf16_t* Wall = (bf16_t*)w; w += (size_t)4 * 512 * 512 * 2;  // Wq|Wk|Wv|Wm contiguous
  bf16_t* Qbf = (bf16_t*)w;  w += (size_t)NQ * 512 * 2;
  bf16_t* KVbf = (bf16_t*)w; w += (size_t)NL * 1024 * 2;
  bf16_t* Msg = (bf16_t*)w;  w += (size_t)NQ * 512 * 2;

  cvt_all<<<dim3(608, 16), 256, 0, stream>>>(guide, low, Wq, Wk, Wv, Wm, Gbf, Lbf, Wall);

  const bf16_t* Gbf_c = Gbf;
  const bf16_t* Lbf_c = Lbf;
  const bf16_t* Wall_c = Wall;
  void* args[] = {(void*)&Gbf_c, (void*)&Lbf_c, (void*)&Wall_c,
                  (void*)&Qbf, (void*)&KVbf, (void*)&Msg,
                  (void*)&gamma, (void*)&beta, (void*)&out};
  hipLaunchCooperativeKernel((void*)mega, dim3(256), dim3(512), args, 0, stream);
}

// Round 8
// 162.824 us; speedup vs baseline: 2.1841x; 2.1841x over previous
//
#include <hip/hip_runtime.h>
#include <hip/hip_bf16.h>
#include <stdint.h>

#define NQ 16384   // 128*128 guide positions
#define NL 1024    // 32*32 low positions

typedef __bf16 bf16_t;
typedef __bf16 bf16x8 __attribute__((ext_vector_type(8)));
typedef __bf16 bf16x4 __attribute__((ext_vector_type(4)));
typedef float f32x4 __attribute__((ext_vector_type(4)));

__device__ __forceinline__ void gload_lds16(const void* g, void* l) {
  __builtin_amdgcn_global_load_lds(
      (const __attribute__((address_space(1))) uint32_t*)g,
      (__attribute__((address_space(3))) uint32_t*)l, 16, 0, 0);
}

// ---- transposes (d-major fp32 -> n-major bf16) + weight cvt, ONE launch ----
__global__ __launch_bounds__(256) void cvt_all(const float* __restrict__ guide,
                                               const float* __restrict__ low,
                                               const float* __restrict__ Wq,
                                               const float* __restrict__ Wk,
                                               const float* __restrict__ Wv,
                                               const float* __restrict__ Wm,
                                               bf16_t* __restrict__ Gbf,
                                               bf16_t* __restrict__ Lbf,
                                               bf16_t* __restrict__ Wall) {
  const int bx = blockIdx.x, by = blockIdx.y, t = threadIdx.x;
  if (bx >= 544) {
    const int idx = (((bx - 544) * 16 + by) * 256 + t) * 4;
    const float* s;
    int off;
    if (idx < 262144)      { s = Wq; off = idx; }
    else if (idx < 524288) { s = Wk; off = idx - 262144; }
    else if (idx < 786432) { s = Wv; off = idx - 524288; }
    else                   { s = Wm; off = idx - 786432; }
    float4 v = *(const float4*)(s + off);
    bf16x4 o = {(bf16_t)v.x, (bf16_t)v.y, (bf16_t)v.z, (bf16_t)v.w};
    *(bf16x4*)(Wall + idx) = o;
    return;
  }
  __shared__ float tl[32][33];
  const float* src;
  bf16_t* dst;
  int ncols, n0;
  if (bx < 512) { src = guide; dst = Gbf; ncols = NQ; n0 = bx * 32; }
  else          { src = low;   dst = Lbf; ncols = NL; n0 = (bx - 512) * 32; }
  const int c0 = by * 32;
  const int c = t & 31, r = t >> 5;
#pragma unroll
  for (int it = 0; it < 4; ++it) {
    int rr = r + it * 8;
    tl[rr][c] = src[(size_t)(c0 + rr) * ncols + n0 + c];
  }
  __syncthreads();
#pragma unroll
  for (int it = 0; it < 4; ++it) {
    int rr = r + it * 8;
    dst[(size_t)(n0 + rr) * 512 + c0 + c] = (bf16_t)tl[c][rr];
  }
}

// ---------------- Q/K/V projections, ONE dispatch, dbuf LDS + bank-balanced swizzle ------
// blocks [0,512): Q = Gbf @ Wq^T; blocks [512,576): KV = Lbf @ [Wk;Wv]^T
// LDS rows are 128 B (BK=64): pre-swizzle global source granule (g ^= r&7), read at
// slot ((kk*4+G) ^ (fr&7)). Linear gload_lds dest preserved (rule: dest = base+lane*16).
__global__ __launch_bounds__(256) void gemm_qkv(const bf16_t* __restrict__ G_,
                                                const bf16_t* __restrict__ Wqb,
                                                bf16_t* __restrict__ Qo,
                                                const bf16_t* __restrict__ L,
                                                const bf16_t* __restrict__ Wkv,
                                                bf16_t* __restrict__ KVo) {
  __shared__ __align__(16) bf16_t As[2][128 * 64];
  __shared__ __align__(16) bf16_t Bs[2][128 * 64];
  const bf16_t *A, *B;
  bf16_t* C;
  int N, bm, bn;
  const int bid = blockIdx.x;
  if (bid < 512) { A = G_; B = Wqb; C = Qo; N = 512; bm = (bid >> 2) * 128; bn = (bid & 3) * 128; }
  else { int id = bid - 512; A = L; B = Wkv; C = KVo; N = 1024; bm = (id >> 3) * 128; bn = (id & 7) * 128; }
  const int t = threadIdx.x;
  const int lane = t & 63;
  const int wave = t >> 6;
  const int wr = (wave >> 1) * 64;
  const int wc = (wave & 1) * 64;
  const int r0 = t >> 3;            // staging row base 0..31
  const int c0 = (t & 7) * 8;       // staging LDS col (elements)
  const int sgc = (((t & 7) ^ ((t >> 3) & 7)) << 3);  // swizzled SOURCE col (elements)
  const int fr = lane & 15;
  const int G = lane >> 4;          // k-granule 0..3
  const int f7 = fr & 7;
  // prologue: stage K-tile 0 into buffer 0
#pragma unroll
  for (int it = 0; it < 4; ++it) {
    const int r = r0 + it * 32;
    gload_lds16(A + (size_t)(bm + r) * 512 + sgc, &As[0][r * 64 + c0]);
    gload_lds16(B + (size_t)(bn + r) * 512 + sgc, &Bs[0][r * 64 + c0]);
  }
  f32x4 acc[4][4] = {};
  __syncthreads();
#pragma unroll 2
  for (int kt = 0; kt < 8; ++kt) {
    const int cur = kt & 1;
    if (kt < 7) {  // issue next-tile stage BEFORE computing current (2-phase)
      const int k0 = (kt + 1) * 64;
#pragma unroll
      for (int it = 0; it < 4; ++it) {
        const int r = r0 + it * 32;
        gload_lds16(A + (size_t)(bm + r) * 512 + k0 + sgc, &As[cur ^ 1][r * 64 + c0]);
        gload_lds16(B + (size_t)(bn + r) * 512 + k0 + sgc, &Bs[cur ^ 1][r * 64 + c0]);
      }
    }
    __builtin_amdgcn_sched_barrier(0);
#pragma unroll
    for (int kk = 0; kk < 2; ++kk) {
      const int slot = (((kk * 4 + G) ^ f7) << 3);  // swizzled read slot (elements)
      bf16x8 af[4], bfv[4];
#pragma unroll
      for (int i = 0; i < 4; ++i)
        af[i] = *(const bf16x8*)&As[cur][(wr + i * 16 + fr) * 64 + slot];
#pragma unroll
      for (int i = 0; i < 4; ++i)
        bfv[i] = *(const bf16x8*)&Bs[cur][(wc + i * 16 + fr) * 64 + slot];
#pragma unroll
      for (int i = 0; i < 4; ++i)
#pragma unroll
        for (int j = 0; j < 4; ++j)
          acc[i][j] = __builtin_amdgcn_mfma_f32_16x16x32_bf16(af[i], bfv[j], acc[i][j], 0, 0, 0);
    }
    __syncthreads();
  }
  const int crow = bm + wr + (G * 4);
  const int ccol = bn + wc + fr;
#pragma unroll
  for (int i = 0; i < 4; ++i)
#pragma unroll
    for (int j = 0; j < 4; ++j) {
      const int row = crow + i * 16;
      const int col = ccol + j * 16;
#pragma unroll
      for (int v = 0; v < 4; ++v)
        C[(size_t)(row + v) * N + col] = (bf16_t)acc[i][j][v];
    }
}

// ---------------- windowed attention, 512 threads/block ----------------
__global__ __launch_bounds__(512) void attn_win(const bf16_t* __restrict__ Q,
                                                const bf16_t* __restrict__ KV,
                                                bf16_t* __restrict__ Msg) {
  __shared__ __align__(16) bf16_t Kl[9 * 512];
  __shared__ __align__(16) bf16_t Vl[9 * 512];
  const int t = threadIdx.x;
  const int lane = t & 63;
  const int wave = t >> 6;
  const int tile = blockIdx.x;
  const int ty = tile >> 5, tx = tile & 31;
  for (int kk = wave; kk < 9; kk += 8) {
    int ky = kk / 3, kx = kk - ky * 3;
    int yy = min(max(ty - 1 + ky, 0), 31);
    int xx = min(max(tx - 1 + kx, 0), 31);
    size_t p = (size_t)(yy * 32 + xx) * 1024;
    *(bf16x8*)&Kl[kk * 512 + lane * 8] = *(const bf16x8*)&KV[p + lane * 8];
    *(bf16x8*)&Vl[kk * 512 + lane * 8] = *(const bf16x8*)&KV[p + 512 + lane * 8];
  }
  __syncthreads();
  const int c = t & 3;
  const int h = (t >> 2) & 7;
  const int pl = t >> 5;
  const int y = ty * 4 + (pl >> 2), x = tx * 4 + (pl & 3);
  const size_t n = (size_t)y * 128 + x;
  const int doff = h * 64 + c * 16;
  const bf16x8 q0 = *(const bf16x8*)(Q + n * 512 + doff);
  const bf16x8 q1 = *(const bf16x8*)(Q + n * 512 + doff + 8);
  float s[9];
#pragma unroll
  for (int k = 0; k < 9; ++k) {
    bf16x8 k0 = *(const bf16x8*)&Kl[k * 512 + doff];
    bf16x8 k1 = *(const bf16x8*)&Kl[k * 512 + doff + 8];
    float p = 0.f;
#pragma unroll
    for (int e = 0; e < 8; ++e) p += (float)q0[e] * (float)k0[e] + (float)q1[e] * (float)k1[e];
    p += __shfl_xor(p, 1, 64);
    p += __shfl_xor(p, 2, 64);
    s[k] = p;
  }
  float mx = s[0];
#pragma unroll
  for (int k = 1; k < 9; ++k) mx = fmaxf(mx, s[k]);
  float sum = 0.f;
#pragma unroll
  for (int k = 0; k < 9; ++k) {
    s[k] = __expf((s[k] - mx) * 0.125f);
    sum += s[k];
  }
  const float inv = 1.0f / sum;
  float acc[16] = {};
#pragma unroll
  for (int k = 0; k < 9; ++k) {
    const float p = s[k] * inv;
    bf16x8 v0 = *(const bf16x8*)&Vl[k * 512 + doff];
    bf16x8 v1 = *(const bf16x8*)&Vl[k * 512 + doff + 8];
#pragma unroll
    for (int e = 0; e < 8; ++e) {
      acc[e] += p * (float)v0[e];
      acc[8 + e] += p * (float)v1[e];
    }
  }
  bf16x8 o0, o1;
#pragma unroll
  for (int e = 0; e < 8; ++e) { o0[e] = (bf16_t)acc[e]; o1[e] = (bf16_t)acc[8 + e]; }
  *(bf16x8*)(Msg + n * 512 + doff) = o0;
  *(bf16x8*)(Msg + n * 512 + doff + 8) = o1;
}

// ------- fused P = Msg @ Wm^T + LayerNorm, v2: 32-row tile, BK=32, 68 KB LDS (2 blk/CU),
// ------- no Cl spill: LN from registers, direct coalesced float4 writes along n --------
__global__ __launch_bounds__(512) void gemm_ln_out(const bf16_t* __restrict__ A,
                                                   const bf16_t* __restrict__ B,
                                                   const float* __restrict__ gamma,
                                                   const float* __restrict__ beta,
                                                   float* __restrict__ out) {
  __shared__ __align__(16) bf16_t As[2][32 * 32];    // 2 KB each
  __shared__ __align__(16) bf16_t Bs[2][512 * 32];   // 32 KB each
  __shared__ float2 part[32][8];
  __shared__ float2 st[32];
  const int t = threadIdx.x;
  const int lane = t & 63;
  const int wave = t >> 6;          // 0..7
  const int wc = wave * 64;         // wave's 64 output cols
  const int bm = blockIdx.x * 32;   // 32 rows per block
  const int fr = lane & 15;
  const int G = lane >> 4;          // 0..3
  const int sr = t >> 2;            // staging row base (B: +it*128; A: 0..31 for t<128)
  const int sc = (t & 3) * 8;       // staging col (elements)
  // prologue: stage K-tile 0
  if (t < 128) gload_lds16(A + (size_t)(bm + sr) * 512 + sc, &As[0][sr * 32 + sc]);
#pragma unroll
  for (int it = 0; it < 4; ++it) {
    const int r = sr + it * 128;
    gload_lds16(B + (size_t)r * 512 + sc, &Bs[0][r * 32 + sc]);
  }
  f32x4 acc[2][4] = {};
  __syncthreads();
#pragma unroll 4
  for (int kt = 0; kt < 16; ++kt) {
    const int cur = kt & 1;
    if (kt < 15) {
      const int k0 = (kt + 1) * 32;
      if (t < 128) gload_lds16(A + (size_t)(bm + sr) * 512 + k0 + sc, &As[cur ^ 1][sr * 32 + sc]);
#pragma unroll
      for (int it = 0; it < 4; ++it) {
        const int r = sr + it * 128;
        gload_lds16(B + (size_t)r * 512 + k0 + sc, &Bs[cur ^ 1][r * 32 + sc]);
      }
    }
    __builtin_amdgcn_sched_barrier(0);
    bf16x8 af[2], bv[4];
#pragma unroll
    for (int i = 0; i < 2; ++i)
      af[i] = *(const bf16x8*)&As[cur][(i * 16 + fr) * 32 + G * 8];
#pragma unroll
    for (int j = 0; j < 4; ++j)
      bv[j] = *(const bf16x8*)&Bs[cur][(wc + j * 16 + fr) * 32 + G * 8];
#pragma unroll
    for (int i = 0; i < 2; ++i)
#pragma unroll
      for (int j = 0; j < 4; ++j)
        acc[i][j] = __builtin_amdgcn_mfma_f32_16x16x32_bf16(af[i], bv[j], acc[i][j], 0, 0, 0);
    __syncthreads();
  }
  // LN partials: thread covers rows {i*16 + G*4 + v}, cols {wc + j*16 + fr}
#pragma unroll
  for (int i = 0; i < 2; ++i)
#pragma unroll
    for (int v = 0; v < 4; ++v) {
      float s = 0.f, s2 = 0.f;
#pragma unroll
      for (int j = 0; j < 4; ++j) {
        float x = acc[i][j][v];
        s += x;
        s2 += x * x;
      }
#pragma unroll
      for (int m = 1; m < 16; m <<= 1) {  // reduce over the 16 col-lanes
        s += __shfl_xor(s, m, 64);
        s2 += __shfl_xor(s2, m, 64);
      }
      if (fr == 0) part[i * 16 + G * 4 + v][wave] = make_float2(s, s2);
    }
  __syncthreads();
  if (t < 32) {
    float s = 0.f, s2 = 0.f;
#pragma unroll
    for (int w = 0; w < 8; ++w) {
      float2 p = part[t][w];
      s += p.x;
      s2 += p.y;
    }
    float mu = s * (1.f / 512.f);
    float var = s2 * (1.f / 512.f) - mu * mu;
    st[t] = make_float2(mu, rsqrtf(var + 1e-5f));
  }
  __syncthreads();
  // apply + write: out[jg][bm + row .. +3] as float4 (rows are the contiguous n dim)
  float2 ms[2][4];
#pragma unroll
  for (int i = 0; i < 2; ++i)
#pragma unroll
    for (int v = 0; v < 4; ++v) ms[i][v] = st[i * 16 + G * 4 + v];
#pragma unroll
  for (int j = 0; j < 4; ++j) {
    const int jg = wc + j * 16 + fr;
    const float g = gamma[jg], b = beta[jg];
#pragma unroll
    for (int i = 0; i < 2; ++i) {
      float4 o;
      o.x = (acc[i][j][0] - ms[i][0].x) * ms[i][0].y * g + b;
      o.y = (acc[i][j][1] - ms[i][1].x) * ms[i][1].y * g + b;
      o.z = (acc[i][j][2] - ms[i][2].x) * ms[i][2].y * g + b;
      o.w = (acc[i][j][3] - ms[i][3].x) * ms[i][3].y * g + b;
      *(float4*)(out + (size_t)jg * NQ + bm + i * 16 + G * 4) = o;
    }
  }
}

extern "C" void kernel_launch(void* const* d_in, const int* in_sizes, int n_in,
                              void* d_out, int out_size, void* d_ws, size_t ws_size,
                              hipStream_t stream) {
  const float* low = (const float*)d_in[0];
  const float* guide = (const float*)d_in[1];
  const float* Wq = (const float*)d_in[2];
  const float* Wk = (const float*)d_in[3];
  const float* Wv = (const float*)d_in[4];
  const float* Wm = (const float*)d_in[5];
  const float* gamma = (const float*)d_in[6];
  const float* beta = (const float*)d_in[7];
  float* out = (float*)d_out;

  char* w = (char*)d_ws;
  bf16_t* Gbf = (bf16_t*)w;  w += (size_t)NQ * 512 * 2;
  bf16_t* Lbf = (bf16_t*)w;  w += (size_t)NL * 512 * 2;
  bf16_t* Wall = (bf16_t*)w; w += (size_t)4 * 512 * 512 * 2;  // Wq|Wk|Wv|Wm contiguous
  bf16_t* Qbf = (bf16_t*)w;  w += (size_t)NQ * 512 * 2;
  bf16_t* KVbf = (bf16_t*)w; w += (size_t)NL * 1024 * 2;
  bf16_t* Msg = (bf16_t*)w;  w += (size_t)NQ * 512 * 2;

  cvt_all<<<dim3(608, 16), 256, 0, stream>>>(guide, low, Wq, Wk, Wv, Wm, Gbf, Lbf, Wall);
  gemm_qkv<<<dim3(576), 256, 0, stream>>>(Gbf, Wall, Qbf, Lbf, Wall + 262144, KVbf);
  attn_win<<<dim3(1024), 512, 0, stream>>>(Qbf, KVbf, Msg);
  gemm_ln_out<<<dim3(NQ / 32), 512, 0, stream>>>(Msg, Wall + 786432, gamma, beta, out);
}

// Round 9
// 159.657 us; speedup vs baseline: 2.2275x; 1.0198x over previous
//
#include <hip/hip_runtime.h>
#include <hip/hip_bf16.h>
#include <stdint.h>

#define NQ 16384   // 128*128 guide positions
#define NL 1024    // 32*32 low positions

typedef __bf16 bf16_t;
typedef __bf16 bf16x8 __attribute__((ext_vector_type(8)));
typedef __bf16 bf16x4 __attribute__((ext_vector_type(4)));
typedef float f32x4 __attribute__((ext_vector_type(4)));

__device__ __forceinline__ void gload_lds16(const void* g, void* l) {
  __builtin_amdgcn_global_load_lds(
      (const __attribute__((address_space(1))) uint32_t*)g,
      (__attribute__((address_space(3))) uint32_t*)l, 16, 0, 0);
}

// ---- transposes (d-major fp32 -> n-major bf16) + weight cvt, ONE launch ----
__global__ __launch_bounds__(256) void cvt_all(const float* __restrict__ guide,
                                               const float* __restrict__ low,
                                               const float* __restrict__ Wq,
                                               const float* __restrict__ Wk,
                                               const float* __restrict__ Wv,
                                               const float* __restrict__ Wm,
                                               bf16_t* __restrict__ Gbf,
                                               bf16_t* __restrict__ Lbf,
                                               bf16_t* __restrict__ Wall) {
  const int bx = blockIdx.x, by = blockIdx.y, t = threadIdx.x;
  if (bx >= 544) {
    const int idx = (((bx - 544) * 16 + by) * 256 + t) * 4;
    const float* s;
    int off;
    if (idx < 262144)      { s = Wq; off = idx; }
    else if (idx < 524288) { s = Wk; off = idx - 262144; }
    else if (idx < 786432) { s = Wv; off = idx - 524288; }
    else                   { s = Wm; off = idx - 786432; }
    float4 v = *(const float4*)(s + off);
    bf16x4 o = {(bf16_t)v.x, (bf16_t)v.y, (bf16_t)v.z, (bf16_t)v.w};
    *(bf16x4*)(Wall + idx) = o;
    return;
  }
  __shared__ float tl[32][33];
  const float* src;
  bf16_t* dst;
  int ncols, n0;
  if (bx < 512) { src = guide; dst = Gbf; ncols = NQ; n0 = bx * 32; }
  else          { src = low;   dst = Lbf; ncols = NL; n0 = (bx - 512) * 32; }
  const int c0 = by * 32;
  const int c = t & 31, r = t >> 5;
#pragma unroll
  for (int it = 0; it < 4; ++it) {
    int rr = r + it * 8;
    tl[rr][c] = src[(size_t)(c0 + rr) * ncols + n0 + c];
  }
  __syncthreads();
#pragma unroll
  for (int it = 0; it < 4; ++it) {
    int rr = r + it * 8;
    dst[(size_t)(n0 + rr) * 512 + c0 + c] = (bf16_t)tl[c][rr];
  }
}

// ---------------- Q/K/V projections, ONE dispatch, dbuf LDS + swizzle + XCD-aware bid ----
// blocks [0,512): Q = Gbf @ Wq^T; blocks [512,576): KV = Lbf @ [Wk;Wv]^T
__global__ __launch_bounds__(256) void gemm_qkv(const bf16_t* __restrict__ G_,
                                                const bf16_t* __restrict__ Wqb,
                                                bf16_t* __restrict__ Qo,
                                                const bf16_t* __restrict__ L,
                                                const bf16_t* __restrict__ Wkv,
                                                bf16_t* __restrict__ KVo) {
  __shared__ __align__(16) bf16_t As[2][128 * 64];
  __shared__ __align__(16) bf16_t Bs[2][128 * 64];
  // T1: bijective XCD swizzle (576 % 8 == 0): blocks sharing an A panel land on one XCD
  const int bid = (blockIdx.x & 7) * 72 + (blockIdx.x >> 3);
  const bf16_t *A, *B;
  bf16_t* C;
  int N, bm, bn;
  if (bid < 512) { A = G_; B = Wqb; C = Qo; N = 512; bm = (bid >> 2) * 128; bn = (bid & 3) * 128; }
  else { int id = bid - 512; A = L; B = Wkv; C = KVo; N = 1024; bm = (id >> 3) * 128; bn = (id & 7) * 128; }
  const int t = threadIdx.x;
  const int lane = t & 63;
  const int wave = t >> 6;
  const int wr = (wave >> 1) * 64;
  const int wc = (wave & 1) * 64;
  const int r0 = t >> 3;            // staging row base 0..31
  const int c0 = (t & 7) * 8;       // staging LDS col (elements)
  const int sgc = (((t & 7) ^ ((t >> 3) & 7)) << 3);  // swizzled SOURCE col (elements)
  const int fr = lane & 15;
  const int G = lane >> 4;          // k-granule 0..3
  const int f7 = fr & 7;
  // prologue: stage K-tile 0 into buffer 0
#pragma unroll
  for (int it = 0; it < 4; ++it) {
    const int r = r0 + it * 32;
    gload_lds16(A + (size_t)(bm + r) * 512 + sgc, &As[0][r * 64 + c0]);
    gload_lds16(B + (size_t)(bn + r) * 512 + sgc, &Bs[0][r * 64 + c0]);
  }
  f32x4 acc[4][4] = {};
  __syncthreads();
#pragma unroll 2
  for (int kt = 0; kt < 8; ++kt) {
    const int cur = kt & 1;
    if (kt < 7) {  // issue next-tile stage BEFORE computing current (2-phase)
      const int k0 = (kt + 1) * 64;
#pragma unroll
      for (int it = 0; it < 4; ++it) {
        const int r = r0 + it * 32;
        gload_lds16(A + (size_t)(bm + r) * 512 + k0 + sgc, &As[cur ^ 1][r * 64 + c0]);
        gload_lds16(B + (size_t)(bn + r) * 512 + k0 + sgc, &Bs[cur ^ 1][r * 64 + c0]);
      }
    }
    __builtin_amdgcn_sched_barrier(0);
#pragma unroll
    for (int kk = 0; kk < 2; ++kk) {
      const int slot = (((kk * 4 + G) ^ f7) << 3);  // swizzled read slot (elements)
      bf16x8 af[4], bfv[4];
#pragma unroll
      for (int i = 0; i < 4; ++i)
        af[i] = *(const bf16x8*)&As[cur][(wr + i * 16 + fr) * 64 + slot];
#pragma unroll
      for (int i = 0; i < 4; ++i)
        bfv[i] = *(const bf16x8*)&Bs[cur][(wc + i * 16 + fr) * 64 + slot];
#pragma unroll
      for (int i = 0; i < 4; ++i)
#pragma unroll
        for (int j = 0; j < 4; ++j)
          acc[i][j] = __builtin_amdgcn_mfma_f32_16x16x32_bf16(af[i], bfv[j], acc[i][j], 0, 0, 0);
    }
    __syncthreads();
  }
  const int crow = bm + wr + (G * 4);
  const int ccol = bn + wc + fr;
#pragma unroll
  for (int i = 0; i < 4; ++i)
#pragma unroll
    for (int j = 0; j < 4; ++j) {
      const int row = crow + i * 16;
      const int col = ccol + j * 16;
#pragma unroll
      for (int v = 0; v < 4; ++v)
        C[(size_t)(row + v) * N + col] = (bf16_t)acc[i][j][v];
    }
}

// ---------------- windowed attention, 512 threads/block ----------------
__global__ __launch_bounds__(512) void attn_win(const bf16_t* __restrict__ Q,
                                                const bf16_t* __restrict__ KV,
                                                bf16_t* __restrict__ Msg) {
  __shared__ __align__(16) bf16_t Kl[9 * 512];
  __shared__ __align__(16) bf16_t Vl[9 * 512];
  const int t = threadIdx.x;
  const int lane = t & 63;
  const int wave = t >> 6;
  const int tile = blockIdx.x;
  const int ty = tile >> 5, tx = tile & 31;
  for (int kk = wave; kk < 9; kk += 8) {
    int ky = kk / 3, kx = kk - ky * 3;
    int yy = min(max(ty - 1 + ky, 0), 31);
    int xx = min(max(tx - 1 + kx, 0), 31);
    size_t p = (size_t)(yy * 32 + xx) * 1024;
    *(bf16x8*)&Kl[kk * 512 + lane * 8] = *(const bf16x8*)&KV[p + lane * 8];
    *(bf16x8*)&Vl[kk * 512 + lane * 8] = *(const bf16x8*)&KV[p + 512 + lane * 8];
  }
  __syncthreads();
  const int c = t & 3;
  const int h = (t >> 2) & 7;
  const int pl = t >> 5;
  const int y = ty * 4 + (pl >> 2), x = tx * 4 + (pl & 3);
  const size_t n = (size_t)y * 128 + x;
  const int doff = h * 64 + c * 16;
  const bf16x8 q0 = *(const bf16x8*)(Q + n * 512 + doff);
  const bf16x8 q1 = *(const bf16x8*)(Q + n * 512 + doff + 8);
  float s[9];
#pragma unroll
  for (int k = 0; k < 9; ++k) {
    bf16x8 k0 = *(const bf16x8*)&Kl[k * 512 + doff];
    bf16x8 k1 = *(const bf16x8*)&Kl[k * 512 + doff + 8];
    float p = 0.f;
#pragma unroll
    for (int e = 0; e < 8; ++e) p += (float)q0[e] * (float)k0[e] + (float)q1[e] * (float)k1[e];
    p += __shfl_xor(p, 1, 64);
    p += __shfl_xor(p, 2, 64);
    s[k] = p;
  }
  float mx = s[0];
#pragma unroll
  for (int k = 1; k < 9; ++k) mx = fmaxf(mx, s[k]);
  float sum = 0.f;
#pragma unroll
  for (int k = 0; k < 9; ++k) {
    s[k] = __expf((s[k] - mx) * 0.125f);
    sum += s[k];
  }
  const float inv = 1.0f / sum;
  float acc[16] = {};
#pragma unroll
  for (int k = 0; k < 9; ++k) {
    const float p = s[k] * inv;
    bf16x8 v0 = *(const bf16x8*)&Vl[k * 512 + doff];
    bf16x8 v1 = *(const bf16x8*)&Vl[k * 512 + doff + 8];
#pragma unroll
    for (int e = 0; e < 8; ++e) {
      acc[e] += p * (float)v0[e];
      acc[8 + e] += p * (float)v1[e];
    }
  }
  bf16x8 o0, o1;
#pragma unroll
  for (int e = 0; e < 8; ++e) { o0[e] = (bf16_t)acc[e]; o1[e] = (bf16_t)acc[8 + e]; }
  *(bf16x8*)(Msg + n * 512 + doff) = o0;
  *(bf16x8*)(Msg + n * 512 + doff + 8) = o1;
}

// ------- fused P = Msg @ Wm^T + LayerNorm, v3: 64-row tile, BK=32, swizzled staging,
// ------- 72 KB LDS (2 blk/CU), LN from registers, coalesced float4 writes along n ------
__global__ __launch_bounds__(512) void gemm_ln_out(const bf16_t* __restrict__ A,
                                                   const bf16_t* __restrict__ B,
                                                   const float* __restrict__ gamma,
                                                   const float* __restrict__ beta,
                                                   float* __restrict__ out) {
  __shared__ __align__(16) bf16_t As[2][64 * 32];    // 4 KB each
  __shared__ __align__(16) bf16_t Bs[2][512 * 32];   // 32 KB each
  __shared__ float2 part[64][8];
  __shared__ float2 st[64];
  const int t = threadIdx.x;
  const int lane = t & 63;
  const int wave = t >> 6;          // 0..7
  const int wc = wave * 64;         // wave's 64 output cols
  const int bm = blockIdx.x * 64;   // 64 rows per block
  const int fr = lane & 15;
  const int G = lane >> 4;          // 0..3
  const int sr = t >> 2;            // staging row base (A: 0..63 for t<256; B: +it*128)
  const int g4 = t & 3;             // staging granule 0..3
  const int sgc = ((g4 ^ (sr & 3)) << 3);  // swizzled SOURCE col (elements), rule #21 pair
  const int slot = (G ^ (fr & 3)) << 3;    // swizzled read slot (elements)
  // prologue: stage K-tile 0
  if (t < 256) gload_lds16(A + (size_t)(bm + sr) * 512 + sgc, &As[0][sr * 32 + g4 * 8]);
#pragma unroll
  for (int it = 0; it < 4; ++it) {
    const int r = sr + it * 128;
    gload_lds16(B + (size_t)r * 512 + sgc, &Bs[0][r * 32 + g4 * 8]);
  }
  f32x4 acc[4][4] = {};
  __syncthreads();
#pragma unroll 4
  for (int kt = 0; kt < 16; ++kt) {
    const int cur = kt & 1;
    if (kt < 15) {
      const int k0 = (kt + 1) * 32;
      if (t < 256) gload_lds16(A + (size_t)(bm + sr) * 512 + k0 + sgc, &As[cur ^ 1][sr * 32 + g4 * 8]);
#pragma unroll
      for (int it = 0; it < 4; ++it) {
        const int r = sr + it * 128;
        gload_lds16(B + (size_t)r * 512 + k0 + sgc, &Bs[cur ^ 1][r * 32 + g4 * 8]);
      }
    }
    __builtin_amdgcn_sched_barrier(0);
    bf16x8 af[4], bv[4];
#pragma unroll
    for (int i = 0; i < 4; ++i)
      af[i] = *(const bf16x8*)&As[cur][(i * 16 + fr) * 32 + slot];
#pragma unroll
    for (int j = 0; j < 4; ++j)
      bv[j] = *(const bf16x8*)&Bs[cur][(wc + j * 16 + fr) * 32 + slot];
#pragma unroll
    for (int i = 0; i < 4; ++i)
#pragma unroll
      for (int j = 0; j < 4; ++j)
        acc[i][j] = __builtin_amdgcn_mfma_f32_16x16x32_bf16(af[i], bv[j], acc[i][j], 0, 0, 0);
    __syncthreads();
  }
  // LN partials: thread covers rows {i*16 + G*4 + v}, cols {wc + j*16 + fr}
#pragma unroll
  for (int i = 0; i < 4; ++i)
#pragma unroll
    for (int v = 0; v < 4; ++v) {
      float s = 0.f, s2 = 0.f;
#pragma unroll
      for (int j = 0; j < 4; ++j) {
        float x = acc[i][j][v];
        s += x;
        s2 += x * x;
      }
#pragma unroll
      for (int m = 1; m < 16; m <<= 1) {  // reduce over the 16 col-lanes
        s += __shfl_xor(s, m, 64);
        s2 += __shfl_xor(s2, m, 64);
      }
      if (fr == 0) part[i * 16 + G * 4 + v][wave] = make_float2(s, s2);
    }
  __syncthreads();
  if (t < 64) {
    float s = 0.f, s2 = 0.f;
#pragma unroll
    for (int w = 0; w < 8; ++w) {
      float2 p = part[t][w];
      s += p.x;
      s2 += p.y;
    }
    float mu = s * (1.f / 512.f);
    float var = s2 * (1.f / 512.f) - mu * mu;
    st[t] = make_float2(mu, rsqrtf(var + 1e-5f));
  }
  __syncthreads();
  // apply + write: out[jg][bm + i*16 + G*4 .. +3] as float4 (rows = contiguous n dim)
  float2 ms[4][4];
#pragma unroll
  for (int i = 0; i < 4; ++i)
#pragma unroll
    for (int v = 0; v < 4; ++v) ms[i][v] = st[i * 16 + G * 4 + v];
#pragma unroll
  for (int j = 0; j < 4; ++j) {
    const int jg = wc + j * 16 + fr;
    const float g = gamma[jg], b = beta[jg];
#pragma unroll
    for (int i = 0; i < 4; ++i) {
      float4 o;
      o.x = (acc[i][j][0] - ms[i][0].x) * ms[i][0].y * g + b;
      o.y = (acc[i][j][1] - ms[i][1].x) * ms[i][1].y * g + b;
      o.z = (acc[i][j][2] - ms[i][2].x) * ms[i][2].y * g + b;
      o.w = (acc[i][j][3] - ms[i][3].x) * ms[i][3].y * g + b;
      *(float4*)(out + (size_t)jg * NQ + bm + i * 16 + G * 4) = o;
    }
  }
}

extern "C" void kernel_launch(void* const* d_in, const int* in_sizes, int n_in,
                              void* d_out, int out_size, void* d_ws, size_t ws_size,
                              hipStream_t stream) {
  const float* low = (const float*)d_in[0];
  const float* guide = (const float*)d_in[1];
  const float* Wq = (const float*)d_in[2];
  const float* Wk = (const float*)d_in[3];
  const float* Wv = (const float*)d_in[4];
  const float* Wm = (const float*)d_in[5];
  const float* gamma = (const float*)d_in[6];
  const float* beta = (const float*)d_in[7];
  float* out = (float*)d_out;

  char* w = (char*)d_ws;
  bf16_t* Gbf = (bf16_t*)w;  w += (size_t)NQ * 512 * 2;
  bf16_t* Lbf = (bf16_t*)w;  w += (size_t)NL * 512 * 2;
  bf16_t* Wall = (bf16_t*)w; w += (size_t)4 * 512 * 512 * 2;  // Wq|Wk|Wv|Wm contiguous
  bf16_t* Qbf = (bf16_t*)w;  w += (size_t)NQ * 512 * 2;
  bf16_t* KVbf = (bf16_t*)w; w += (size_t)NL * 1024 * 2;
  bf16_t* Msg = (bf16_t*)w;  w += (size_t)NQ * 512 * 2;

  cvt_all<<<dim3(608, 16), 256, 0, stream>>>(guide, low, Wq, Wk, Wv, Wm, Gbf, Lbf, Wall);
  gemm_qkv<<<dim3(576), 256, 0, stream>>>(Gbf, Wall, Qbf, Lbf, Wall + 262144, KVbf);
  attn_win<<<dim3(1024), 512, 0, stream>>>(Qbf, KVbf, Msg);
  gemm_ln_out<<<dim3(NQ / 64), 512, 0, stream>>>(Msg, Wall + 786432, gamma, beta, out);
}